// Round 4
// baseline (12333.534 us; speedup 1.0000x reference)
//
#include <hip/hip_runtime.h>
#include <hip/hip_bf16.h>
#include <stdint.h>

#define N_ENT  100000
#define N_EDGE 400000
#define DIM    256
#define N_SEED 10000

typedef unsigned short u16;

__device__ __forceinline__ float bf16_to_f(u16 u) {
    union { uint32_t i; float f; } v;
    v.i = ((uint32_t)u) << 16;
    return v.f;
}
__device__ __forceinline__ u16 f_to_bf16(float f) {
    union { uint32_t i; float f; } v; v.f = f;
    uint32_t x = v.i;
    return (u16)((x + 0x7FFFu + ((x >> 16) & 1u)) >> 16);  // round-nearest-even
}

// ---- dtype detect: flag=1 if inputs are packed bf16, 0 if f32 ----
__global__ void detect_kernel(const void* feats, int* flag) {
    __shared__ int bad;
    if (threadIdx.x == 0) bad = 0;
    __syncthreads();
    const u16* p = (const u16*)feats;
    float v = fabsf(bf16_to_f(p[threadIdx.x]));
    if (!(v <= 0.01f)) atomicOr(&bad, 1);   // NaN also lands here
    __syncthreads();
    if (threadIdx.x == 0) *flag = bad ? 0 : 1;
}

// ---- degree accumulate (into dinv buffer as float) ----
__global__ void degree_kernel(const int* __restrict__ edges, float* __restrict__ deg) {
    int e = blockIdx.x * blockDim.x + threadIdx.x;
    if (e < N_EDGE) {
        atomicAdd(&deg[edges[2 * e]],     1.0f);
        atomicAdd(&deg[edges[2 * e + 1]], 1.0f);
    }
}

// ---- deg -> rsqrt(deg + 1) in place (self loop accounted here) ----
__global__ void dinv_kernel(float* __restrict__ deg) {
    int i = blockIdx.x * blockDim.x + threadIdx.x;
    if (i < N_ENT) deg[i] = rsqrtf(deg[i] + 1.0f);
}

// pair id -> (src, dst):  [0,E): fwd  [E,2E): rev  [2E,2E+N): self loop
__device__ __forceinline__ void pair_sd(int gw, const int* __restrict__ edges, int& s, int& d) {
    if (gw < N_EDGE)          { s = edges[2 * gw];            d = edges[2 * gw + 1]; }
    else if (gw < 2 * N_EDGE) { int e = gw - N_EDGE; s = edges[2 * e + 1]; d = edges[2 * e]; }
    else                      { s = d = gw - 2 * N_EDGE; }
}

// ---- layer 1: gather feats (bf16 or f32 per flag) -> atomic scatter f32 ----
__global__ void scatter1_kernel(const void* __restrict__ feats, const int* __restrict__ edges,
                                const float* __restrict__ dinv, float* __restrict__ out,
                                const int* __restrict__ flag) {
    int gid  = blockIdx.x * blockDim.x + threadIdx.x;
    int gw   = gid >> 6;           // one wave per directed pair
    int lane = threadIdx.x & 63;
    if (gw >= 2 * N_EDGE + N_ENT) return;
    int s, d; pair_sd(gw, edges, s, d);
    float w = dinv[s] * dinv[d];
    int base_s = s * DIM + lane * 4;
    int base_d = d * DIM + lane * 4;
    float x0, x1, x2, x3;
    if (*flag) {
        ushort4 q = *(const ushort4*)((const u16*)feats + base_s);   // 8B coalesced
        x0 = bf16_to_f(q.x); x1 = bf16_to_f(q.y); x2 = bf16_to_f(q.z); x3 = bf16_to_f(q.w);
    } else {
        float4 q = *(const float4*)((const float*)feats + base_s);   // 16B coalesced
        x0 = q.x; x1 = q.y; x2 = q.z; x3 = q.w;
    }
    atomicAdd(&out[base_d],     x0 * w);
    atomicAdd(&out[base_d + 1], x1 * w);
    atomicAdd(&out[base_d + 2], x2 * w);
    atomicAdd(&out[base_d + 3], x3 * w);
}

// ---- layer 2: gather f32 h1 with fused ReLU -> atomic scatter f32 ----
__global__ void scatter2_kernel(const float* __restrict__ h, const int* __restrict__ edges,
                                const float* __restrict__ dinv, float* __restrict__ out) {
    int gid  = blockIdx.x * blockDim.x + threadIdx.x;
    int gw   = gid >> 6;
    int lane = threadIdx.x & 63;
    if (gw >= 2 * N_EDGE + N_ENT) return;
    int s, d; pair_sd(gw, edges, s, d);
    float w = dinv[s] * dinv[d];
    int base_s = s * DIM + lane * 4;
    int base_d = d * DIM + lane * 4;
    float4 q = *(const float4*)(h + base_s);
    atomicAdd(&out[base_d],     fmaxf(q.x, 0.0f) * w);
    atomicAdd(&out[base_d + 1], fmaxf(q.y, 0.0f) * w);
    atomicAdd(&out[base_d + 2], fmaxf(q.z, 0.0f) * w);
    atomicAdd(&out[base_d + 3], fmaxf(q.w, 0.0f) * w);
}

// ---- row L2-normalize, write ent output (bf16 or f32 per flag) ----
__global__ void norm_kernel(const float* __restrict__ h, void* __restrict__ out,
                            long long ent_off, const int* __restrict__ flag) {
    int row = blockIdx.x;
    int t   = threadIdx.x;               // 256 threads = 4 waves
    float v  = h[row * DIM + t];
    float sq = v * v;
    #pragma unroll
    for (int o = 32; o > 0; o >>= 1) sq += __shfl_down(sq, o, 64);
    __shared__ float part[4];
    if ((t & 63) == 0) part[t >> 6] = sq;
    __syncthreads();
    float norm2 = part[0] + part[1] + part[2] + part[3];
    float inv = 1.0f / fmaxf(sqrtf(norm2), 1e-12f);
    float o = v * inv;
    long long idx = ent_off + (long long)row * DIM + t;
    if (*flag) ((u16*)out)[idx]  = f_to_bf16(o);
    else       ((float*)out)[idx] = o;
}

// ---- seed gather from the already-written ent region ----
__global__ void seed_kernel(const int* __restrict__ seeds, void* __restrict__ out,
                            long long ent_off, long long seed_off, const int* __restrict__ flag) {
    int i = blockIdx.x;
    int t = threadIdx.x;
    int s = seeds[i];
    long long src = ent_off  + (long long)s * DIM + t;
    long long dst = seed_off + (long long)i * DIM + t;
    if (*flag) ((u16*)out)[dst]  = ((const u16*)out)[src];
    else       ((float*)out)[dst] = ((const float*)out)[src];
}

extern "C" void kernel_launch(void* const* d_in, const int* in_sizes, int n_in,
                              void* d_out, int out_size, void* d_ws, size_t ws_size,
                              hipStream_t stream) {
    const void* feats_sr = d_in[0];
    const void* feats_tg = d_in[1];
    const int*  edges_sr = (const int*)d_in[2];
    const int*  edges_tg = (const int*)d_in[3];
    const int*  sr_seeds = (const int*)d_in[4];
    const int*  tg_seeds = (const int*)d_in[5];
    // triples (d_in[6], d_in[7]) are unused by the reference output

    char*  ws   = (char*)d_ws;
    int*   flag = (int*)ws;
    float* dinv = (float*)(ws + 256);
    float* h1   = (float*)(ws + 256 + 400128);           // N_ENT*4 rounded to 256
    float* h2   = h1 + (size_t)N_ENT * DIM;
    // zero region: dinv..h2 contiguous
    const size_t zero_bytes = 400128 + 2 * (size_t)N_ENT * DIM * 4;

    detect_kernel<<<1, 256, 0, stream>>>(feats_sr, flag);

    const int npairs = 2 * N_EDGE + N_ENT;               // 900000
    const int nblk   = (npairs + 3) / 4;                 // 4 waves (pairs) per 256-thr block

    for (int side = 0; side < 2; ++side) {
        const void* feats = side ? feats_tg : feats_sr;
        const int*  edges = side ? edges_tg : edges_sr;
        const int*  seeds = side ? tg_seeds : sr_seeds;
        long long seed_off = (long long)side * N_SEED * DIM;
        long long ent_off  = (long long)2 * N_SEED * DIM + (long long)side * N_ENT * DIM;

        hipMemsetAsync(dinv, 0, zero_bytes, stream);     // dinv + h1 + h2 in one shot

        degree_kernel<<<(N_EDGE + 255) / 256, 256, 0, stream>>>(edges, dinv);
        dinv_kernel<<<(N_ENT + 255) / 256, 256, 0, stream>>>(dinv);
        scatter1_kernel<<<nblk, 256, 0, stream>>>(feats, edges, dinv, h1, flag);
        scatter2_kernel<<<nblk, 256, 0, stream>>>(h1, edges, dinv, h2);
        norm_kernel<<<N_ENT, 256, 0, stream>>>(h2, d_out, ent_off, flag);
        seed_kernel<<<N_SEED, 256, 0, stream>>>(seeds, d_out, ent_off, seed_off, flag);
    }
}

// Round 5
// 1474.522 us; speedup vs baseline: 8.3644x; 8.3644x over previous
//
#include <hip/hip_runtime.h>
#include <hip/hip_bf16.h>
#include <stdint.h>

#define N_ENT  100000
#define N_EDGE 400000
#define DIM    256
#define N_SEED 10000
#define SCAN_T 1024

typedef unsigned short u16;

__device__ __forceinline__ float bf16_to_f(u16 u) {
    union { uint32_t i; float f; } v;
    v.i = ((uint32_t)u) << 16;
    return v.f;
}
__device__ __forceinline__ u16 f_to_bf16(float f) {
    union { uint32_t i; float f; } v; v.f = f;
    uint32_t x = v.i;
    return (u16)((x + 0x7FFFu + ((x >> 16) & 1u)) >> 16);  // round-nearest-even
}

// ---- dtype detect: flag=1 if inputs are packed bf16, 0 if f32 ----
__global__ void detect_kernel(const void* feats, int* flag) {
    __shared__ int bad;
    if (threadIdx.x == 0) bad = 0;
    __syncthreads();
    const u16* p = (const u16*)feats;
    float v = fabsf(bf16_to_f(p[threadIdx.x]));
    if (!(v <= 0.01f)) atomicOr(&bad, 1);
    __syncthreads();
    if (threadIdx.x == 0) *flag = bad ? 0 : 1;
}

// ---- integer degree count over both edge directions ----
__global__ void degcnt_kernel(const int* __restrict__ edges, int* __restrict__ deg) {
    int e = blockIdx.x * blockDim.x + threadIdx.x;
    if (e < N_EDGE) {
        atomicAdd(&deg[edges[2 * e]],     1);
        atomicAdd(&deg[edges[2 * e + 1]], 1);
    }
}

// ---- dinv[i] = rsqrt(deg_i + 1)  (self loop) ----
__global__ void dinv_kernel(const int* __restrict__ deg, float* __restrict__ dinv) {
    int i = blockIdx.x * blockDim.x + threadIdx.x;
    if (i < N_ENT) dinv[i] = rsqrtf((float)deg[i] + 1.0f);
}

// ---- single-block exclusive prefix scan: deg -> rowptr (+cursor copy) ----
__global__ void scan_kernel(const int* __restrict__ deg, int* __restrict__ rowptr,
                            int* __restrict__ cursor) {
    __shared__ int lds[SCAN_T];
    int t = threadIdx.x;
    const int chunk = (N_ENT + SCAN_T - 1) / SCAN_T;
    int lo = t * chunk, hi = lo + chunk;
    if (lo > N_ENT) lo = N_ENT;
    if (hi > N_ENT) hi = N_ENT;
    int s = 0;
    for (int i = lo; i < hi; ++i) s += deg[i];
    lds[t] = s;
    __syncthreads();
    for (int o = 1; o < SCAN_T; o <<= 1) {
        int u = (t >= o) ? lds[t - o] : 0;
        __syncthreads();
        lds[t] += u;
        __syncthreads();
    }
    int run = lds[t] - s;                 // exclusive prefix of this chunk
    for (int i = lo; i < hi; ++i) {
        rowptr[i] = run; cursor[i] = run;
        run += deg[i];
    }
    if (t == SCAN_T - 1) rowptr[N_ENT] = run;   // total = 2E
}

// ---- CSR fill: both directions of every edge ----
__global__ void fill_kernel(const int* __restrict__ edges, int* __restrict__ cursor,
                            int* __restrict__ colx) {
    int e = blockIdx.x * blockDim.x + threadIdx.x;
    if (e >= N_EDGE) return;
    int a = edges[2 * e], b = edges[2 * e + 1];
    colx[atomicAdd(&cursor[b], 1)] = a;   // pair a->b
    colx[atomicAdd(&cursor[a], 1)] = b;   // pair b->a
}

// ---- layer 1 pull: one wave per dst row; ReLU fused into write ----
__global__ void pull1_kernel(const void* __restrict__ feats, const int* __restrict__ rowptr,
                             const int* __restrict__ colx, const float* __restrict__ dinv,
                             float* __restrict__ h1, const int* __restrict__ flag) {
    int gw   = (blockIdx.x * blockDim.x + threadIdx.x) >> 6;
    if (gw >= N_ENT) return;
    int lane = threadIdx.x & 63, off = lane * 4;
    int d = gw;
    int k = rowptr[d], end = rowptr[d + 1];
    float dd = dinv[d];
    int use_bf = *flag;
    float a0, a1, a2, a3;
    {   // self loop, weight dinv[d]^2
        float w = dd * dd, x0, x1, x2, x3;
        if (use_bf) {
            ushort4 q = *(const ushort4*)((const u16*)feats + d * DIM + off);
            x0 = bf16_to_f(q.x); x1 = bf16_to_f(q.y); x2 = bf16_to_f(q.z); x3 = bf16_to_f(q.w);
        } else {
            float4 q = *(const float4*)((const float*)feats + d * DIM + off);
            x0 = q.x; x1 = q.y; x2 = q.z; x3 = q.w;
        }
        a0 = x0 * w; a1 = x1 * w; a2 = x2 * w; a3 = x3 * w;
    }
    if (k < end) {
        int c = colx[k];
        for (;;) {
            int cn = (k + 1 < end) ? colx[k + 1] : 0;   // prefetch next index
            float w = dinv[c] * dd, x0, x1, x2, x3;
            if (use_bf) {
                ushort4 q = *(const ushort4*)((const u16*)feats + c * DIM + off);
                x0 = bf16_to_f(q.x); x1 = bf16_to_f(q.y); x2 = bf16_to_f(q.z); x3 = bf16_to_f(q.w);
            } else {
                float4 q = *(const float4*)((const float*)feats + c * DIM + off);
                x0 = q.x; x1 = q.y; x2 = q.z; x3 = q.w;
            }
            a0 += x0 * w; a1 += x1 * w; a2 += x2 * w; a3 += x3 * w;
            if (++k >= end) break;
            c = cn;
        }
    }
    float4 o;
    o.x = fmaxf(a0, 0.0f); o.y = fmaxf(a1, 0.0f);
    o.z = fmaxf(a2, 0.0f); o.w = fmaxf(a3, 0.0f);
    *(float4*)(h1 + d * DIM + off) = o;
}

// ---- layer 2 pull + fused L2-normalize + output write ----
__global__ void pull2_kernel(const float* __restrict__ h1, const int* __restrict__ rowptr,
                             const int* __restrict__ colx, const float* __restrict__ dinv,
                             void* __restrict__ out, long long ent_off,
                             const int* __restrict__ flag) {
    int gw   = (blockIdx.x * blockDim.x + threadIdx.x) >> 6;
    if (gw >= N_ENT) return;
    int lane = threadIdx.x & 63, off = lane * 4;
    int d = gw;
    int k = rowptr[d], end = rowptr[d + 1];
    float dd = dinv[d];
    float w = dd * dd;
    float4 q = *(const float4*)(h1 + d * DIM + off);     // self loop
    float a0 = q.x * w, a1 = q.y * w, a2 = q.z * w, a3 = q.w * w;
    if (k < end) {
        int c = colx[k];
        for (;;) {
            int cn = (k + 1 < end) ? colx[k + 1] : 0;
            float wc = dinv[c] * dd;
            float4 v = *(const float4*)(h1 + c * DIM + off);
            a0 += v.x * wc; a1 += v.y * wc; a2 += v.z * wc; a3 += v.w * wc;
            if (++k >= end) break;
            c = cn;
        }
    }
    float sq = a0 * a0 + a1 * a1 + a2 * a2 + a3 * a3;
    #pragma unroll
    for (int o = 1; o < 64; o <<= 1) sq += __shfl_xor(sq, o, 64);
    float inv = 1.0f / fmaxf(sqrtf(sq), 1e-12f);
    long long idx = ent_off + (long long)d * DIM + off;
    if (*flag) {
        ushort4 r;
        r.x = f_to_bf16(a0 * inv); r.y = f_to_bf16(a1 * inv);
        r.z = f_to_bf16(a2 * inv); r.w = f_to_bf16(a3 * inv);
        *(ushort4*)((u16*)out + idx) = r;
    } else {
        float4 r = { a0 * inv, a1 * inv, a2 * inv, a3 * inv };
        *(float4*)((float*)out + idx) = r;
    }
}

// ---- seed gather from the already-written ent region ----
__global__ void seed_kernel(const int* __restrict__ seeds, void* __restrict__ out,
                            long long ent_off, long long seed_off, const int* __restrict__ flag) {
    int i = blockIdx.x;
    int t = threadIdx.x;
    int s = seeds[i];
    long long src = ent_off  + (long long)s * DIM + t;
    long long dst = seed_off + (long long)i * DIM + t;
    if (*flag) ((u16*)out)[dst]  = ((const u16*)out)[src];
    else       ((float*)out)[dst] = ((const float*)out)[src];
}

extern "C" void kernel_launch(void* const* d_in, const int* in_sizes, int n_in,
                              void* d_out, int out_size, void* d_ws, size_t ws_size,
                              hipStream_t stream) {
    const void* feats_sr = d_in[0];
    const void* feats_tg = d_in[1];
    const int*  edges_sr = (const int*)d_in[2];
    const int*  edges_tg = (const int*)d_in[3];
    const int*  sr_seeds = (const int*)d_in[4];
    const int*  tg_seeds = (const int*)d_in[5];

    // workspace layout (all 256B-aligned)
    char* ws = (char*)d_ws;
    int*   flag   = (int*)ws;                                   //   256 B
    int*   deg    = (int*)(ws + 256);                           //   400 KB
    float* dinv   = (float*)(ws + 256 + 400128);                //   400 KB
    int*   rowptr = (int*)(ws + 256 + 2 * 400128);              //   400 KB (+4)
    int*   cursor = (int*)(ws + 256 + 3 * 400128);              //   400 KB
    int*   colx   = (int*)(ws + 256 + 4 * 400128);              //   3.2 MB
    float* h1     = (float*)(ws + 256 + 4 * 400128 + 3200256);  // 102.4 MB
    // total ≈ 107 MB

    detect_kernel<<<1, 256, 0, stream>>>(feats_sr, flag);

    const int pull_blk = (N_ENT + 3) / 4;     // 4 waves (rows) per 256-thr block

    for (int side = 0; side < 2; ++side) {
        const void* feats = side ? feats_tg : feats_sr;
        const int*  edges = side ? edges_tg : edges_sr;
        const int*  seeds = side ? tg_seeds : sr_seeds;
        long long seed_off = (long long)side * N_SEED * DIM;
        long long ent_off  = (long long)2 * N_SEED * DIM + (long long)side * N_ENT * DIM;

        hipMemsetAsync(deg, 0, (size_t)N_ENT * 4, stream);

        degcnt_kernel<<<(N_EDGE + 255) / 256, 256, 0, stream>>>(edges, deg);
        dinv_kernel<<<(N_ENT + 255) / 256, 256, 0, stream>>>(deg, dinv);
        scan_kernel<<<1, SCAN_T, 0, stream>>>(deg, rowptr, cursor);
        fill_kernel<<<(N_EDGE + 255) / 256, 256, 0, stream>>>(edges, cursor, colx);
        pull1_kernel<<<pull_blk, 256, 0, stream>>>(feats, rowptr, colx, dinv, h1, flag);
        pull2_kernel<<<pull_blk, 256, 0, stream>>>(h1, rowptr, colx, dinv, d_out, ent_off, flag);
        seed_kernel<<<N_SEED, 256, 0, stream>>>(seeds, d_out, ent_off, seed_off, flag);
    }
}

// Round 6
// 1071.185 us; speedup vs baseline: 11.5139x; 1.3765x over previous
//
#include <hip/hip_runtime.h>
#include <hip/hip_bf16.h>
#include <stdint.h>

#define N_ENT  100000
#define N_EDGE 400000
#define DIM    256
#define N_SEED 10000
#define SBLK   1024                      // elements scanned per block
#define NSB    98                        // ceil(N_ENT / SBLK)
#define RP_STRIDE (N_ENT + 64)           // rowptr per-side stride (ints)

typedef unsigned short u16;

__device__ __forceinline__ float bf16_to_f(u16 u) {
    union { uint32_t i; float f; } v;
    v.i = ((uint32_t)u) << 16;
    return v.f;
}
__device__ __forceinline__ u16 f_to_bf16(float f) {
    union { uint32_t i; float f; } v; v.f = f;
    uint32_t x = v.i;
    return (u16)((x + 0x7FFFu + ((x >> 16) & 1u)) >> 16);  // round-nearest-even
}

// ---- dtype detect: flag=1 if inputs are packed bf16, 0 if f32 ----
__global__ void detect_kernel(const void* feats, int* flag) {
    __shared__ int bad;
    if (threadIdx.x == 0) bad = 0;
    __syncthreads();
    const u16* p = (const u16*)feats;
    float v = fabsf(bf16_to_f(p[threadIdx.x]));
    if (!(v <= 0.01f)) atomicOr(&bad, 1);
    __syncthreads();
    if (threadIdx.x == 0) *flag = bad ? 0 : 1;
}

// ---- degree count, both sides (blockIdx.y = side) ----
__global__ void degcnt2_kernel(const int* __restrict__ e_sr, const int* __restrict__ e_tg,
                               int* __restrict__ deg) {
    int e = blockIdx.x * blockDim.x + threadIdx.x;
    if (e >= N_EDGE) return;
    const int* ed = blockIdx.y ? e_tg : e_sr;
    int* dg = deg + blockIdx.y * N_ENT;
    atomicAdd(&dg[ed[2 * e]],     1);
    atomicAdd(&dg[ed[2 * e + 1]], 1);
}

// ---- dinv = rsqrt(deg + 1), both sides ----
__global__ void dinv2_kernel(const int* __restrict__ deg, float* __restrict__ dinv) {
    int i = blockIdx.x * blockDim.x + threadIdx.x;
    if (i < N_ENT) {
        int j = blockIdx.y * N_ENT + i;
        dinv[j] = rsqrtf((float)deg[j] + 1.0f);
    }
}

// ---- scan phase A: per-block reduce of 1024 degrees ----
__global__ void scanA_kernel(const int* __restrict__ deg, int* __restrict__ bsum) {
    int side = blockIdx.y;
    const int* d = deg + side * N_ENT;
    int t = threadIdx.x;
    int base = blockIdx.x * SBLK + t * 4;
    int v0 = 0, v1 = 0, v2 = 0, v3 = 0;
    if (base + 3 < N_ENT) {
        int4 q = *(const int4*)(d + base);
        v0 = q.x; v1 = q.y; v2 = q.z; v3 = q.w;
    } else {
        if (base     < N_ENT) v0 = d[base];
        if (base + 1 < N_ENT) v1 = d[base + 1];
        if (base + 2 < N_ENT) v2 = d[base + 2];
    }
    int s = v0 + v1 + v2 + v3;
    #pragma unroll
    for (int o = 1; o < 64; o <<= 1) s += __shfl_xor(s, o, 64);
    __shared__ int lds[4];
    if ((t & 63) == 0) lds[t >> 6] = s;
    __syncthreads();
    if (t == 0) bsum[side * 128 + blockIdx.x] = lds[0] + lds[1] + lds[2] + lds[3];
}

// ---- scan phase B: scan the 98 block sums (1 small block per side) ----
__global__ void scanB_kernel(const int* __restrict__ bsum, int* __restrict__ boff,
                             int* __restrict__ rowptr) {
    int side = blockIdx.y;
    __shared__ int lds[128];
    int t = threadIdx.x;
    int v = (t < NSB) ? bsum[side * 128 + t] : 0;
    lds[t] = v;
    __syncthreads();
    for (int o = 1; o < 128; o <<= 1) {
        int u = (t >= o) ? lds[t - o] : 0;
        __syncthreads();
        lds[t] += u;
        __syncthreads();
    }
    if (t < NSB) boff[side * 128 + t] = lds[t] - v;      // exclusive
    if (t == 0)  rowptr[side * RP_STRIDE + N_ENT] = 2 * N_EDGE;  // total is exact
}

// ---- scan phase C: in-block exclusive scan + block offset -> rowptr, cursor ----
__global__ void scanC_kernel(const int* __restrict__ deg, const int* __restrict__ boff,
                             int* __restrict__ rowptr, int* __restrict__ cursor) {
    int side = blockIdx.y;
    const int* d = deg + side * N_ENT;
    int* rp = rowptr + side * RP_STRIDE;
    int* cu = cursor + side * N_ENT;
    int t = threadIdx.x;
    int lane = t & 63, wave = t >> 6;
    int base = blockIdx.x * SBLK + t * 4;
    int v0 = 0, v1 = 0, v2 = 0, v3 = 0;
    if (base + 3 < N_ENT) {
        int4 q = *(const int4*)(d + base);
        v0 = q.x; v1 = q.y; v2 = q.z; v3 = q.w;
    } else {
        if (base     < N_ENT) v0 = d[base];
        if (base + 1 < N_ENT) v1 = d[base + 1];
        if (base + 2 < N_ENT) v2 = d[base + 2];
    }
    int s = v0 + v1 + v2 + v3;
    int incl = s;
    #pragma unroll
    for (int o = 1; o < 64; o <<= 1) {
        int u = __shfl_up(incl, o, 64);
        if (lane >= o) incl += u;
    }
    int wexcl = incl - s;
    __shared__ int lds[4];
    if (lane == 63) lds[wave] = incl;
    __syncthreads();
    int wsum = 0;
    for (int w = 0; w < wave; ++w) wsum += lds[w];
    int off = boff[side * 128 + blockIdx.x] + wsum + wexcl;
    int e0 = off, e1 = off + v0, e2 = e1 + v1, e3 = e2 + v2;
    if (base     < N_ENT) { rp[base]     = e0; cu[base]     = e0; }
    if (base + 1 < N_ENT) { rp[base + 1] = e1; cu[base + 1] = e1; }
    if (base + 2 < N_ENT) { rp[base + 2] = e2; cu[base + 2] = e2; }
    if (base + 3 < N_ENT) { rp[base + 3] = e3; cu[base + 3] = e3; }
}

// ---- CSR fill, both sides ----
__global__ void fill2_kernel(const int* __restrict__ e_sr, const int* __restrict__ e_tg,
                             int* __restrict__ cursor, int* __restrict__ colx) {
    int e = blockIdx.x * blockDim.x + threadIdx.x;
    if (e >= N_EDGE) return;
    const int* ed = blockIdx.y ? e_tg : e_sr;
    int* cu = cursor + blockIdx.y * N_ENT;
    int* cx = colx   + blockIdx.y * (2 * N_EDGE);
    int a = ed[2 * e], b = ed[2 * e + 1];
    cx[atomicAdd(&cu[b], 1)] = a;
    cx[atomicAdd(&cu[a], 1)] = b;
}

// ---- layer 1 pull: one wave per dst row; ReLU fused into write ----
__global__ void pull1_kernel(const void* __restrict__ feats, const int* __restrict__ rowptr,
                             const int* __restrict__ colx, const float* __restrict__ dinv,
                             float* __restrict__ h1, const int* __restrict__ flag) {
    int gw   = (blockIdx.x * blockDim.x + threadIdx.x) >> 6;
    if (gw >= N_ENT) return;
    int lane = threadIdx.x & 63, off = lane * 4;
    int d = gw;
    int k = rowptr[d], end = rowptr[d + 1];
    float dd = dinv[d];
    int use_bf = *flag;
    float a0, a1, a2, a3;
    {   // self loop, weight dinv[d]^2
        float w = dd * dd, x0, x1, x2, x3;
        if (use_bf) {
            ushort4 q = *(const ushort4*)((const u16*)feats + d * DIM + off);
            x0 = bf16_to_f(q.x); x1 = bf16_to_f(q.y); x2 = bf16_to_f(q.z); x3 = bf16_to_f(q.w);
        } else {
            float4 q = *(const float4*)((const float*)feats + d * DIM + off);
            x0 = q.x; x1 = q.y; x2 = q.z; x3 = q.w;
        }
        a0 = x0 * w; a1 = x1 * w; a2 = x2 * w; a3 = x3 * w;
    }
    if (k < end) {
        int c = colx[k];
        for (;;) {
            int cn = (k + 1 < end) ? colx[k + 1] : 0;   // prefetch next index
            float w = dinv[c] * dd, x0, x1, x2, x3;
            if (use_bf) {
                ushort4 q = *(const ushort4*)((const u16*)feats + c * DIM + off);
                x0 = bf16_to_f(q.x); x1 = bf16_to_f(q.y); x2 = bf16_to_f(q.z); x3 = bf16_to_f(q.w);
            } else {
                float4 q = *(const float4*)((const float*)feats + c * DIM + off);
                x0 = q.x; x1 = q.y; x2 = q.z; x3 = q.w;
            }
            a0 += x0 * w; a1 += x1 * w; a2 += x2 * w; a3 += x3 * w;
            if (++k >= end) break;
            c = cn;
        }
    }
    float4 o;
    o.x = fmaxf(a0, 0.0f); o.y = fmaxf(a1, 0.0f);
    o.z = fmaxf(a2, 0.0f); o.w = fmaxf(a3, 0.0f);
    *(float4*)(h1 + d * DIM + off) = o;
}

// ---- layer 2 pull + fused L2-normalize + output write ----
__global__ void pull2_kernel(const float* __restrict__ h1, const int* __restrict__ rowptr,
                             const int* __restrict__ colx, const float* __restrict__ dinv,
                             void* __restrict__ out, long long ent_off,
                             const int* __restrict__ flag) {
    int gw   = (blockIdx.x * blockDim.x + threadIdx.x) >> 6;
    if (gw >= N_ENT) return;
    int lane = threadIdx.x & 63, off = lane * 4;
    int d = gw;
    int k = rowptr[d], end = rowptr[d + 1];
    float dd = dinv[d];
    float w = dd * dd;
    float4 q = *(const float4*)(h1 + d * DIM + off);     // self loop
    float a0 = q.x * w, a1 = q.y * w, a2 = q.z * w, a3 = q.w * w;
    if (k < end) {
        int c = colx[k];
        for (;;) {
            int cn = (k + 1 < end) ? colx[k + 1] : 0;
            float wc = dinv[c] * dd;
            float4 v = *(const float4*)(h1 + c * DIM + off);
            a0 += v.x * wc; a1 += v.y * wc; a2 += v.z * wc; a3 += v.w * wc;
            if (++k >= end) break;
            c = cn;
        }
    }
    float sq = a0 * a0 + a1 * a1 + a2 * a2 + a3 * a3;
    #pragma unroll
    for (int o = 1; o < 64; o <<= 1) sq += __shfl_xor(sq, o, 64);
    float inv = 1.0f / fmaxf(sqrtf(sq), 1e-12f);
    long long idx = ent_off + (long long)d * DIM + off;
    if (*flag) {
        ushort4 r;
        r.x = f_to_bf16(a0 * inv); r.y = f_to_bf16(a1 * inv);
        r.z = f_to_bf16(a2 * inv); r.w = f_to_bf16(a3 * inv);
        *(ushort4*)((u16*)out + idx) = r;
    } else {
        float4 r = { a0 * inv, a1 * inv, a2 * inv, a3 * inv };
        *(float4*)((float*)out + idx) = r;
    }
}

// ---- seed gather from the already-written ent region ----
__global__ void seed_kernel(const int* __restrict__ seeds, void* __restrict__ out,
                            long long ent_off, long long seed_off, const int* __restrict__ flag) {
    int i = blockIdx.x;
    int t = threadIdx.x;
    int s = seeds[i];
    long long src = ent_off  + (long long)s * DIM + t;
    long long dst = seed_off + (long long)i * DIM + t;
    if (*flag) ((u16*)out)[dst]  = ((const u16*)out)[src];
    else       ((float*)out)[dst] = ((const float*)out)[src];
}

extern "C" void kernel_launch(void* const* d_in, const int* in_sizes, int n_in,
                              void* d_out, int out_size, void* d_ws, size_t ws_size,
                              hipStream_t stream) {
    const void* feats_sr = d_in[0];
    const void* feats_tg = d_in[1];
    const int*  edges_sr = (const int*)d_in[2];
    const int*  edges_tg = (const int*)d_in[3];
    const int*  sr_seeds = (const int*)d_in[4];
    const int*  tg_seeds = (const int*)d_in[5];

    // workspace layout (256B-aligned offsets)
    char* ws = (char*)d_ws;
    int*   flag   = (int*)ws;                       // 256 B
    int*   deg    = (int*)(ws + 256);               // 2 sides × 400000 B (pad 800256)
    float* dinv   = (float*)(ws + 800512);          // 800256
    int*   rowptr = (int*)(ws + 1600768);           // 2 × RP_STRIDE ints = 800512
    int*   cursor = (int*)(ws + 2401280);           // 800256
    int*   bsum   = (int*)(ws + 3201536);           // 1024
    int*   boff   = (int*)(ws + 3202560);           // 1024
    int*   colx   = (int*)(ws + 3203584);           // 2 × 3.2 MB = 6400256
    float* h1     = (float*)(ws + 9603840);         // 102.4 MB (single side, reused)
    // total ≈ 112 MB

    detect_kernel<<<1, 256, 0, stream>>>(feats_sr, flag);

    hipMemsetAsync(deg, 0, (size_t)2 * N_ENT * 4, stream);

    dim3 eg((N_EDGE + 255) / 256, 2);
    dim3 ng((N_ENT + 255) / 256, 2);
    dim3 sg(NSB, 2);
    degcnt2_kernel<<<eg, 256, 0, stream>>>(edges_sr, edges_tg, deg);
    dinv2_kernel<<<ng, 256, 0, stream>>>(deg, dinv);
    scanA_kernel<<<sg, 256, 0, stream>>>(deg, bsum);
    scanB_kernel<<<dim3(1, 2), 128, 0, stream>>>(bsum, boff, rowptr);
    scanC_kernel<<<sg, 256, 0, stream>>>(deg, boff, rowptr, cursor);
    fill2_kernel<<<eg, 256, 0, stream>>>(edges_sr, edges_tg, cursor, colx);

    const int pull_blk = (N_ENT + 3) / 4;     // 4 waves (rows) per 256-thr block

    for (int side = 0; side < 2; ++side) {
        const void* feats = side ? feats_tg : feats_sr;
        const int*  seeds = side ? tg_seeds : sr_seeds;
        const int*  rp    = rowptr + side * RP_STRIDE;
        const int*  cx    = colx   + side * (2 * N_EDGE);
        const float* dv   = dinv   + side * N_ENT;
        long long seed_off = (long long)side * N_SEED * DIM;
        long long ent_off  = (long long)2 * N_SEED * DIM + (long long)side * N_ENT * DIM;

        pull1_kernel<<<pull_blk, 256, 0, stream>>>(feats, rp, cx, dv, h1, flag);
        pull2_kernel<<<pull_blk, 256, 0, stream>>>(h1, rp, cx, dv, d_out, ent_off, flag);
        seed_kernel<<<N_SEED, 256, 0, stream>>>(seeds, d_out, ent_off, seed_off, flag);
    }
}

// Round 7
// 941.506 us; speedup vs baseline: 13.0998x; 1.1377x over previous
//
#include <hip/hip_runtime.h>
#include <hip/hip_bf16.h>
#include <stdint.h>

#define N_ENT  100000
#define N_EDGE 400000
#define DIM    256
#define N_SEED 10000
#define SBLK   1024                      // elements scanned per block
#define NSB    98                        // ceil(N_ENT / SBLK)
#define RP_STRIDE (N_ENT + 64)           // rowptr per-side stride (ints)

typedef unsigned short u16;

__device__ __forceinline__ float bf16_to_f(u16 u) {
    union { uint32_t i; float f; } v;
    v.i = ((uint32_t)u) << 16;
    return v.f;
}
__device__ __forceinline__ u16 f_to_bf16(float f) {
    union { uint32_t i; float f; } v; v.f = f;
    uint32_t x = v.i;
    return (u16)((x + 0x7FFFu + ((x >> 16) & 1u)) >> 16);  // round-nearest-even
}

// ---- dtype detect: flag=1 if inputs are packed bf16, 0 if f32 ----
__global__ void detect_kernel(const void* feats, int* flag) {
    __shared__ int bad;
    if (threadIdx.x == 0) bad = 0;
    __syncthreads();
    const u16* p = (const u16*)feats;
    float v = fabsf(bf16_to_f(p[threadIdx.x]));
    if (!(v <= 0.01f)) atomicOr(&bad, 1);
    __syncthreads();
    if (threadIdx.x == 0) *flag = bad ? 0 : 1;
}

// ---- degree count, both sides (blockIdx.y = side) ----
__global__ void degcnt2_kernel(const int* __restrict__ e_sr, const int* __restrict__ e_tg,
                               int* __restrict__ deg) {
    int e = blockIdx.x * blockDim.x + threadIdx.x;
    if (e >= N_EDGE) return;
    const int* ed = blockIdx.y ? e_tg : e_sr;
    int* dg = deg + blockIdx.y * N_ENT;
    atomicAdd(&dg[ed[2 * e]],     1);
    atomicAdd(&dg[ed[2 * e + 1]], 1);
}

// ---- dinv = rsqrt(deg + 1), both sides ----
__global__ void dinv2_kernel(const int* __restrict__ deg, float* __restrict__ dinv) {
    int i = blockIdx.x * blockDim.x + threadIdx.x;
    if (i < N_ENT) {
        int j = blockIdx.y * N_ENT + i;
        dinv[j] = rsqrtf((float)deg[j] + 1.0f);
    }
}

// ---- scan phase A: per-block reduce of 1024 degrees ----
__global__ void scanA_kernel(const int* __restrict__ deg, int* __restrict__ bsum) {
    int side = blockIdx.y;
    const int* d = deg + side * N_ENT;
    int t = threadIdx.x;
    int base = blockIdx.x * SBLK + t * 4;
    int v0 = 0, v1 = 0, v2 = 0, v3 = 0;
    if (base + 3 < N_ENT) {
        int4 q = *(const int4*)(d + base);
        v0 = q.x; v1 = q.y; v2 = q.z; v3 = q.w;
    } else {
        if (base     < N_ENT) v0 = d[base];
        if (base + 1 < N_ENT) v1 = d[base + 1];
        if (base + 2 < N_ENT) v2 = d[base + 2];
    }
    int s = v0 + v1 + v2 + v3;
    #pragma unroll
    for (int o = 1; o < 64; o <<= 1) s += __shfl_xor(s, o, 64);
    __shared__ int lds[4];
    if ((t & 63) == 0) lds[t >> 6] = s;
    __syncthreads();
    if (t == 0) bsum[side * 128 + blockIdx.x] = lds[0] + lds[1] + lds[2] + lds[3];
}

// ---- scan phase B: scan the 98 block sums (1 small block per side) ----
__global__ void scanB_kernel(const int* __restrict__ bsum, int* __restrict__ boff,
                             int* __restrict__ rowptr) {
    int side = blockIdx.y;
    __shared__ int lds[128];
    int t = threadIdx.x;
    int v = (t < NSB) ? bsum[side * 128 + t] : 0;
    lds[t] = v;
    __syncthreads();
    for (int o = 1; o < 128; o <<= 1) {
        int u = (t >= o) ? lds[t - o] : 0;
        __syncthreads();
        lds[t] += u;
        __syncthreads();
    }
    if (t < NSB) boff[side * 128 + t] = lds[t] - v;      // exclusive
    if (t == 0)  rowptr[side * RP_STRIDE + N_ENT] = 2 * N_EDGE;  // total is exact
}

// ---- scan phase C: in-block exclusive scan + block offset -> rowptr, cursor ----
__global__ void scanC_kernel(const int* __restrict__ deg, const int* __restrict__ boff,
                             int* __restrict__ rowptr, int* __restrict__ cursor) {
    int side = blockIdx.y;
    const int* d = deg + side * N_ENT;
    int* rp = rowptr + side * RP_STRIDE;
    int* cu = cursor + side * N_ENT;
    int t = threadIdx.x;
    int lane = t & 63, wave = t >> 6;
    int base = blockIdx.x * SBLK + t * 4;
    int v0 = 0, v1 = 0, v2 = 0, v3 = 0;
    if (base + 3 < N_ENT) {
        int4 q = *(const int4*)(d + base);
        v0 = q.x; v1 = q.y; v2 = q.z; v3 = q.w;
    } else {
        if (base     < N_ENT) v0 = d[base];
        if (base + 1 < N_ENT) v1 = d[base + 1];
        if (base + 2 < N_ENT) v2 = d[base + 2];
    }
    int s = v0 + v1 + v2 + v3;
    int incl = s;
    #pragma unroll
    for (int o = 1; o < 64; o <<= 1) {
        int u = __shfl_up(incl, o, 64);
        if (lane >= o) incl += u;
    }
    int wexcl = incl - s;
    __shared__ int lds[4];
    if (lane == 63) lds[wave] = incl;
    __syncthreads();
    int wsum = 0;
    for (int w = 0; w < wave; ++w) wsum += lds[w];
    int off = boff[side * 128 + blockIdx.x] + wsum + wexcl;
    int e0 = off, e1 = off + v0, e2 = e1 + v1, e3 = e2 + v2;
    if (base     < N_ENT) { rp[base]     = e0; cu[base]     = e0; }
    if (base + 1 < N_ENT) { rp[base + 1] = e1; cu[base + 1] = e1; }
    if (base + 2 < N_ENT) { rp[base + 2] = e2; cu[base + 2] = e2; }
    if (base + 3 < N_ENT) { rp[base + 3] = e3; cu[base + 3] = e3; }
}

// ---- CSR fill, both sides ----
__global__ void fill2_kernel(const int* __restrict__ e_sr, const int* __restrict__ e_tg,
                             int* __restrict__ cursor, int* __restrict__ colx) {
    int e = blockIdx.x * blockDim.x + threadIdx.x;
    if (e >= N_EDGE) return;
    const int* ed = blockIdx.y ? e_tg : e_sr;
    int* cu = cursor + blockIdx.y * N_ENT;
    int* cx = colx   + blockIdx.y * (2 * N_EDGE);
    int a = ed[2 * e], b = ed[2 * e + 1];
    cx[atomicAdd(&cu[b], 1)] = a;
    cx[atomicAdd(&cu[a], 1)] = b;
}

// ---- layer 1 pull, both sides: wave per dst row, 2-way unroll, bf16 h1 out ----
__global__ void pull1_kernel(const void* __restrict__ feats_sr, const void* __restrict__ feats_tg,
                             const int* __restrict__ rowptr, const int* __restrict__ colx,
                             const float* __restrict__ dinv, u16* __restrict__ h1,
                             const int* __restrict__ flag) {
    int side = blockIdx.y;
    int gw   = (blockIdx.x * blockDim.x + threadIdx.x) >> 6;
    if (gw >= N_ENT) return;
    int lane = threadIdx.x & 63, off = lane * 4;
    const void*  feats = side ? feats_tg : feats_sr;
    const int*   rp = rowptr + side * RP_STRIDE;
    const int*   cx = colx   + side * (2 * N_EDGE);
    const float* dv = dinv   + side * N_ENT;
    u16*         h  = h1 + (size_t)side * N_ENT * DIM;
    int d = gw;
    int k = rp[d], end = rp[d + 1];
    float dd = dv[d];
    int use_bf = *flag;
    float a0, a1, a2, a3;
    {   // self loop, weight dinv[d]^2
        float w = dd * dd;
        if (use_bf) {
            ushort4 q = *(const ushort4*)((const u16*)feats + d * DIM + off);
            a0 = bf16_to_f(q.x) * w; a1 = bf16_to_f(q.y) * w;
            a2 = bf16_to_f(q.z) * w; a3 = bf16_to_f(q.w) * w;
        } else {
            float4 q = *(const float4*)((const float*)feats + d * DIM + off);
            a0 = q.x * w; a1 = q.y * w; a2 = q.z * w; a3 = q.w * w;
        }
    }
    while (k + 2 <= end) {              // 2 independent row-gathers in flight
        int c0 = cx[k], c1 = cx[k + 1];
        float w0 = dv[c0] * dd, w1 = dv[c1] * dd;
        if (use_bf) {
            ushort4 q0 = *(const ushort4*)((const u16*)feats + c0 * DIM + off);
            ushort4 q1 = *(const ushort4*)((const u16*)feats + c1 * DIM + off);
            a0 += bf16_to_f(q0.x) * w0 + bf16_to_f(q1.x) * w1;
            a1 += bf16_to_f(q0.y) * w0 + bf16_to_f(q1.y) * w1;
            a2 += bf16_to_f(q0.z) * w0 + bf16_to_f(q1.z) * w1;
            a3 += bf16_to_f(q0.w) * w0 + bf16_to_f(q1.w) * w1;
        } else {
            float4 q0 = *(const float4*)((const float*)feats + c0 * DIM + off);
            float4 q1 = *(const float4*)((const float*)feats + c1 * DIM + off);
            a0 += q0.x * w0 + q1.x * w1;
            a1 += q0.y * w0 + q1.y * w1;
            a2 += q0.z * w0 + q1.z * w1;
            a3 += q0.w * w0 + q1.w * w1;
        }
        k += 2;
    }
    if (k < end) {
        int c = cx[k];
        float w = dv[c] * dd;
        if (use_bf) {
            ushort4 q = *(const ushort4*)((const u16*)feats + c * DIM + off);
            a0 += bf16_to_f(q.x) * w; a1 += bf16_to_f(q.y) * w;
            a2 += bf16_to_f(q.z) * w; a3 += bf16_to_f(q.w) * w;
        } else {
            float4 q = *(const float4*)((const float*)feats + c * DIM + off);
            a0 += q.x * w; a1 += q.y * w; a2 += q.z * w; a3 += q.w * w;
        }
    }
    ushort4 r;                          // ReLU fused, store bf16
    r.x = f_to_bf16(fmaxf(a0, 0.0f)); r.y = f_to_bf16(fmaxf(a1, 0.0f));
    r.z = f_to_bf16(fmaxf(a2, 0.0f)); r.w = f_to_bf16(fmaxf(a3, 0.0f));
    *(ushort4*)(h + d * DIM + off) = r;
}

// ---- layer 2 pull, both sides: bf16 h1 in, fused L2-norm, 2-way unroll ----
__global__ void pull2_kernel(const u16* __restrict__ h1, const int* __restrict__ rowptr,
                             const int* __restrict__ colx, const float* __restrict__ dinv,
                             void* __restrict__ out, const int* __restrict__ flag) {
    int side = blockIdx.y;
    int gw   = (blockIdx.x * blockDim.x + threadIdx.x) >> 6;
    if (gw >= N_ENT) return;
    int lane = threadIdx.x & 63, off = lane * 4;
    const int*   rp = rowptr + side * RP_STRIDE;
    const int*   cx = colx   + side * (2 * N_EDGE);
    const float* dv = dinv   + side * N_ENT;
    const u16*   h  = h1 + (size_t)side * N_ENT * DIM;
    long long ent_off = (long long)2 * N_SEED * DIM + (long long)side * N_ENT * DIM;
    int d = gw;
    int k = rp[d], end = rp[d + 1];
    float dd = dv[d];
    float w = dd * dd;
    ushort4 qs = *(const ushort4*)(h + d * DIM + off);   // self loop
    float a0 = bf16_to_f(qs.x) * w, a1 = bf16_to_f(qs.y) * w;
    float a2 = bf16_to_f(qs.z) * w, a3 = bf16_to_f(qs.w) * w;
    while (k + 2 <= end) {
        int c0 = cx[k], c1 = cx[k + 1];
        float w0 = dv[c0] * dd, w1 = dv[c1] * dd;
        ushort4 q0 = *(const ushort4*)(h + c0 * DIM + off);
        ushort4 q1 = *(const ushort4*)(h + c1 * DIM + off);
        a0 += bf16_to_f(q0.x) * w0 + bf16_to_f(q1.x) * w1;
        a1 += bf16_to_f(q0.y) * w0 + bf16_to_f(q1.y) * w1;
        a2 += bf16_to_f(q0.z) * w0 + bf16_to_f(q1.z) * w1;
        a3 += bf16_to_f(q0.w) * w0 + bf16_to_f(q1.w) * w1;
        k += 2;
    }
    if (k < end) {
        int c = cx[k];
        float wc = dv[c] * dd;
        ushort4 q = *(const ushort4*)(h + c * DIM + off);
        a0 += bf16_to_f(q.x) * wc; a1 += bf16_to_f(q.y) * wc;
        a2 += bf16_to_f(q.z) * wc; a3 += bf16_to_f(q.w) * wc;
    }
    float sq = a0 * a0 + a1 * a1 + a2 * a2 + a3 * a3;
    #pragma unroll
    for (int o = 1; o < 64; o <<= 1) sq += __shfl_xor(sq, o, 64);
    float inv = 1.0f / fmaxf(sqrtf(sq), 1e-12f);
    long long idx = ent_off + (long long)d * DIM + off;
    if (*flag) {
        ushort4 r;
        r.x = f_to_bf16(a0 * inv); r.y = f_to_bf16(a1 * inv);
        r.z = f_to_bf16(a2 * inv); r.w = f_to_bf16(a3 * inv);
        *(ushort4*)((u16*)out + idx) = r;
    } else {
        float4 r = { a0 * inv, a1 * inv, a2 * inv, a3 * inv };
        *(float4*)((float*)out + idx) = r;
    }
}

// ---- seed gather, both sides ----
__global__ void seed2_kernel(const int* __restrict__ s_sr, const int* __restrict__ s_tg,
                             void* __restrict__ out, const int* __restrict__ flag) {
    int side = blockIdx.y;
    int i = blockIdx.x;
    int t = threadIdx.x;
    const int* seeds = side ? s_tg : s_sr;
    long long ent_off  = (long long)2 * N_SEED * DIM + (long long)side * N_ENT * DIM;
    long long seed_off = (long long)side * N_SEED * DIM;
    int s = seeds[i];
    long long src = ent_off  + (long long)s * DIM + t;
    long long dst = seed_off + (long long)i * DIM + t;
    if (*flag) ((u16*)out)[dst]  = ((const u16*)out)[src];
    else       ((float*)out)[dst] = ((const float*)out)[src];
}

extern "C" void kernel_launch(void* const* d_in, const int* in_sizes, int n_in,
                              void* d_out, int out_size, void* d_ws, size_t ws_size,
                              hipStream_t stream) {
    const void* feats_sr = d_in[0];
    const void* feats_tg = d_in[1];
    const int*  edges_sr = (const int*)d_in[2];
    const int*  edges_tg = (const int*)d_in[3];
    const int*  sr_seeds = (const int*)d_in[4];
    const int*  tg_seeds = (const int*)d_in[5];

    // workspace layout (256B-aligned offsets)
    char* ws = (char*)d_ws;
    int*   flag   = (int*)ws;                       // 256 B
    int*   deg    = (int*)(ws + 256);               // 2 × 400000 B (pad 800256)
    float* dinv   = (float*)(ws + 800512);          // 800256
    int*   rowptr = (int*)(ws + 1600768);           // 2 × RP_STRIDE ints = 800512
    int*   cursor = (int*)(ws + 2401280);           // 800256
    int*   bsum   = (int*)(ws + 3201536);           // 1024
    int*   boff   = (int*)(ws + 3202560);           // 1024
    int*   colx   = (int*)(ws + 3203584);           // 2 × 3.2 MB = 6400256
    u16*   h1     = (u16*)(ws + 9603840);           // 2 × 51.2 MB bf16
    // total ≈ 112 MB

    detect_kernel<<<1, 256, 0, stream>>>(feats_sr, flag);

    hipMemsetAsync(deg, 0, (size_t)2 * N_ENT * 4, stream);

    dim3 eg((N_EDGE + 255) / 256, 2);
    dim3 ng((N_ENT + 255) / 256, 2);
    dim3 sg(NSB, 2);
    degcnt2_kernel<<<eg, 256, 0, stream>>>(edges_sr, edges_tg, deg);
    dinv2_kernel<<<ng, 256, 0, stream>>>(deg, dinv);
    scanA_kernel<<<sg, 256, 0, stream>>>(deg, bsum);
    scanB_kernel<<<dim3(1, 2), 128, 0, stream>>>(bsum, boff, rowptr);
    scanC_kernel<<<sg, 256, 0, stream>>>(deg, boff, rowptr, cursor);
    fill2_kernel<<<eg, 256, 0, stream>>>(edges_sr, edges_tg, cursor, colx);

    dim3 pg((N_ENT + 3) / 4, 2);              // 4 rows (waves) per block × 2 sides
    pull1_kernel<<<pg, 256, 0, stream>>>(feats_sr, feats_tg, rowptr, colx, dinv, h1, flag);
    pull2_kernel<<<pg, 256, 0, stream>>>(h1, rowptr, colx, dinv, d_out, flag);
    seed2_kernel<<<dim3(N_SEED, 2), 256, 0, stream>>>(sr_seeds, tg_seeds, d_out, flag);
}